// Round 10
// baseline (311.977 us; speedup 1.0000x reference)
//
#include <hip/hip_runtime.h>

#define KK 27
#define INC 32
#define PC 64

typedef __attribute__((ext_vector_type(8))) short v8s;
typedef __attribute__((ext_vector_type(4))) float f32x4;

static __device__ __forceinline__ float b2f(ushort u) {
  union { float f; unsigned int i; } x; x.i = ((unsigned int)u) << 16; return x.f;
}
static __device__ __forceinline__ ushort f2b(float f) {
  union { float f; unsigned int i; } x; x.f = f;
  unsigned int u = x.i;
  unsigned int r = (u + 0x7FFFu + ((u >> 16) & 1u)) >> 16;
  return (ushort)r;
}

// ---------------- Kernel 1: x = relu(xf@Wt+bt) [bf16], v = relu(x@Wv+bv) [bf16]
__global__ __launch_bounds__(256) void k_prep(
    const float* __restrict__ xf, const float* __restrict__ Wt, const float* __restrict__ bt,
    const float* __restrict__ Wv, const float* __restrict__ bv,
    ushort* __restrict__ x, ushort* __restrict__ v, int N)
{
  int tid = threadIdx.x, lane = tid & 63, w = tid >> 6;
  int vbase = blockIdx.x * 16;
  __shared__ float xin[16][32];
  __shared__ float xs[16][64];
  if (tid < 128) {
    int r = tid >> 3, c4 = tid & 7;
    int n = vbase + r;
    float4 d = make_float4(0.f, 0.f, 0.f, 0.f);
    if (n < N) d = *(const float4*)(xf + (size_t)n * INC + c4 * 4);
    *(float4*)(&xin[r][c4 * 4]) = d;
  }
  __syncthreads();
  float a0 = bt[lane], a1 = a0, a2 = a0, a3 = a0;
  #pragma unroll
  for (int i = 0; i < INC; ++i) {
    float wt = Wt[i * PC + lane];
    a0 += xin[w * 4 + 0][i] * wt; a1 += xin[w * 4 + 1][i] * wt;
    a2 += xin[w * 4 + 2][i] * wt; a3 += xin[w * 4 + 3][i] * wt;
  }
  a0 = fmaxf(a0, 0.f); a1 = fmaxf(a1, 0.f); a2 = fmaxf(a2, 0.f); a3 = fmaxf(a3, 0.f);
  xs[w * 4 + 0][lane] = a0; xs[w * 4 + 1][lane] = a1;
  xs[w * 4 + 2][lane] = a2; xs[w * 4 + 3][lane] = a3;
  {
    int n0 = vbase + w * 4;
    if (n0 + 0 < N) x[(size_t)(n0 + 0) * PC + lane] = f2b(a0);
    if (n0 + 1 < N) x[(size_t)(n0 + 1) * PC + lane] = f2b(a1);
    if (n0 + 2 < N) x[(size_t)(n0 + 2) * PC + lane] = f2b(a2);
    if (n0 + 3 < N) x[(size_t)(n0 + 3) * PC + lane] = f2b(a3);
  }
  float v0 = bv[lane], v1 = v0, v2 = v0, v3 = v0;
  #pragma unroll
  for (int i = 0; i < PC; ++i) {
    float wv = Wv[i * PC + lane];
    v0 += xs[w * 4 + 0][i] * wv; v1 += xs[w * 4 + 1][i] * wv;
    v2 += xs[w * 4 + 2][i] * wv; v3 += xs[w * 4 + 3][i] * wv;
  }
  {
    int n0 = vbase + w * 4;
    if (n0 + 0 < N) v[(size_t)(n0 + 0) * PC + lane] = f2b(fmaxf(v0, 0.f));
    if (n0 + 1 < N) v[(size_t)(n0 + 1) * PC + lane] = f2b(fmaxf(v1, 0.f));
    if (n0 + 2 < N) v[(size_t)(n0 + 2) * PC + lane] = f2b(fmaxf(v2, 0.f));
    if (n0 + 3 < N) v[(size_t)(n0 + 3) * PC + lane] = f2b(fmaxf(v3, 0.f));
  }
}

// ---------------- Kernel 2: q + softmax attn. 16 voxels/block, 16 lanes/voxel.
__global__ __launch_bounds__(256) void k_attn(
    const ushort* __restrict__ x, const int* __restrict__ nbr_idx, const int* __restrict__ nbr_mask,
    const int* __restrict__ coords,
    const float* __restrict__ Wpos, const float* __restrict__ bpos,
    const float* __restrict__ Wq, const float* __restrict__ bq,
    const float* __restrict__ proj, float* __restrict__ attn, int N)
{
  int tid = threadIdx.x;
  int g = tid >> 4, l = tid & 15;
  int nb = blockIdx.x * 16;
  int n = nb + g;
  __shared__ int jm[16][KK];
  __shared__ int cds[16][3];
  for (int i = tid; i < 16 * KK; i += 256) {
    int r = i / KK, k = i % KK;
    int nn = nb + r;
    int val = -1;
    if (nn < N && nbr_mask[(size_t)nn * KK + k]) val = nbr_idx[(size_t)nn * KK + k];
    jm[r][k] = val;
  }
  if (tid < 48) {
    int r = tid / 3, c = tid % 3;
    int nn = nb + r;
    cds[r][c] = (nn < N) ? coords[nn * 3 + c] : 0;
  }
  __syncthreads();
  if (n >= N) return;
  int ch = l * 4;
  float4 wp0 = *(const float4*)(Wpos + 0 * PC + ch);
  float4 wp1 = *(const float4*)(Wpos + 1 * PC + ch);
  float4 wp2 = *(const float4*)(Wpos + 2 * PC + ch);
  float4 bp  = *(const float4*)(bpos + ch);
  int cx = cds[g][0], cy = cds[g][1], cz = cds[g][2];
  float q0 = 0.f, q1 = 0.f, q2 = 0.f, q3 = 0.f;

  int ja = jm[g][0], jb = jm[g][1];
  ushort4 xva, xvb; int cxa, cya, cza, cxb, cyb, czb;
  {
    int jj = max(ja, 0);
    xva = *(const ushort4*)(x + (size_t)jj * PC + ch);
    cxa = coords[jj * 3 + 0]; cya = coords[jj * 3 + 1]; cza = coords[jj * 3 + 2];
  }
  {
    int jj = max(jb, 0);
    xvb = *(const ushort4*)(x + (size_t)jj * PC + ch);
    cxb = coords[jj * 3 + 0]; cyb = coords[jj * 3 + 1]; czb = coords[jj * 3 + 2];
  }

  for (int k = 0; k < KK; ++k) {
    int jc = ja;
    ushort4 xv = xva;
    int jx = cxa, jy = cya, jz = cza;
    ja = jb; xva = xvb; cxa = cxb; cya = cyb; cza = czb;
    int jn = (k + 2 < KK) ? jm[g][k + 2] : -1;
    jb = jn;
    {
      int jj = max(jn, 0);
      xvb = *(const ushort4*)(x + (size_t)jj * PC + ch);
      cxb = coords[jj * 3 + 0]; cyb = coords[jj * 3 + 1]; czb = coords[jj * 3 + 2];
    }
    float msk = (jc >= 0) ? 1.f : 0.f;
    float rx = (float)(jx - cx);
    float ry = (float)(jy - cy);
    float rz = (float)(jz - cz);
    float4 wq = *(const float4*)(Wq + k * PC + ch);
    float p0 = fmaxf(rx * wp0.x + ry * wp1.x + rz * wp2.x + bp.x, 0.f);
    float p1 = fmaxf(rx * wp0.y + ry * wp1.y + rz * wp2.y + bp.y, 0.f);
    float p2 = fmaxf(rx * wp0.z + ry * wp1.z + rz * wp2.z + bp.z, 0.f);
    float p3 = fmaxf(rx * wp0.w + ry * wp1.w + rz * wp2.w + bp.w, 0.f);
    q0 += msk * (b2f(xv.x) + p0) * wq.x;
    q1 += msk * (b2f(xv.y) + p1) * wq.y;
    q2 += msk * (b2f(xv.z) + p2) * wq.z;
    q3 += msk * (b2f(xv.w) + p3) * wq.w;
  }
  float qs = q0 + q1 + q2 + q3;
  #pragma unroll
  for (int off = 1; off < 16; off <<= 1) qs += __shfl_xor(qs, off);
  if (l == 0) {
    float q = fmaxf(qs + bq[0], 0.f);
    float lg[4], mx = -1e30f;
    #pragma unroll
    for (int m = 0; m < 4; ++m) { lg[m] = q * proj[m] * 0.1f; mx = fmaxf(mx, lg[m]); }
    float s = 0.f;
    #pragma unroll
    for (int m = 0; m < 4; ++m) { lg[m] = __expf(lg[m] - mx); s += lg[m]; }
    float inv = 1.f / s;
    #pragma unroll
    for (int m = 0; m < 4; ++m) attn[(size_t)n * 4 + m] = lg[m] * inv;
  }
}

// ---------------- Kernel 3: repack W_code f32 [m,k,c,d] -> bf16 Bp[s][kg][col][j]
__global__ __launch_bounds__(256) void k_prepB(const float* __restrict__ Wcode, ushort* __restrict__ Bp)
{
  int i = blockIdx.x * 256 + threadIdx.x;   // 54*4*256*8 = 442368
  int j = i & 7;
  int col = (i >> 3) & 255;
  int kg = (i >> 11) & 3;
  int s = i >> 13;
  int k = s * 32 + kg * 8 + j;
  int m = col >> 6, d = col & 63;
  int knbr = k >> 6, c = k & 63;
  Bp[i] = f2b(Wcode[(((m * KK + knbr) * 64) + c) * 64 + d]);
}

// ---------------- Kernel 3b: Wd f32 [k=32][d=64] -> bf16 Wdp[d][k] (B-fragment layout)
__global__ __launch_bounds__(256) void k_prepD(const float* __restrict__ Wd, ushort* __restrict__ Wdp)
{
  int i = blockIdx.x * 256 + threadIdx.x;   // 2048
  int col = i >> 5, k = i & 31;
  Wdp[i] = f2b(Wd[k * PC + col]);
}

// ---------------- Kernel 4: gathered GEMM [64x1728]x[1728x256], 8 waves (512 thr):
// wave w = (row-half w>>2, d-slice w&3); acc[2][4] = 32 AGPRs/wave (half of R9)
// -> combined VGPR+AGPR ~100 -> 4 waves/SIMD. Per-lane m-sum epilogue kept.
// 3-buffer LDS ring, early commit, B-before-gather.
__global__ __launch_bounds__(512) void k_code(
    const ushort* __restrict__ v, const int* __restrict__ nbr_idx, const int* __restrict__ nbr_mask,
    const ushort* __restrict__ Bp, const float* __restrict__ attn,
    const float* __restrict__ xf, const ushort* __restrict__ Wdp, const float* __restrict__ bd,
    const float* __restrict__ bcode, float* __restrict__ out, int N)
{
  const int tid = threadIdx.x;
  const int lane = tid & 63, w = tid >> 6;       // w in 0..7
  const int rh = w >> 2, ds = w & 3;             // row-half, d-slice
  const int base = blockIdx.x * 64;

  __shared__ __align__(16) union SM {
    struct { ushort As[3][4096]; int jm[64][KK]; } g;   // GEMM phase (31.5 KB)
    struct { ushort xfb[64][40]; } e;                   // epilogue (5.1 KB)
  } sm;

  for (int i = tid; i < 64 * KK; i += 512) {
    int r = i / KK, k = i % KK;
    int n = base + r;
    int val = -1;
    if (n < N && nbr_mask[(size_t)n * KK + k]) val = nbr_idx[(size_t)n * KK + k];
    sm.g.jm[r][k] = val;
  }

  // staging: one uint4 per thread (512 threads cover 64 rows x 8 chunks)
  const int r0 = tid >> 3, cc0 = tid & 7;
  const int sc0 = cc0 ^ (r0 & 7);

  __syncthreads();  // jm ready

  // prologue: gather(0) -> As[0]; gather(1) -> reg R
  uint4 R0 = make_uint4(0u,0u,0u,0u);
  {
    int j0 = sm.g.jm[r0][0];
    uint4 p0 = make_uint4(0u, 0u, 0u, 0u);
    if (j0 >= 0) p0 = *(const uint4*)(v + (size_t)j0 * PC + cc0 * 8);
    int jc = sm.g.jm[r0][1];
    if (jc >= 0) R0 = *(const uint4*)(v + (size_t)jc * PC + cc0 * 8);
    *(uint4*)(&sm.g.As[0][r0 * 64 + sc0 * 8]) = p0;
  }
  __syncthreads();

  f32x4 acc[2][4] = {};
  // col = nt*64 + ds*16 + (lane&15)  -> nt stride = 512 ushorts
  const ushort* bbase = Bp + (size_t)(lane >> 4) * 2048 + (size_t)((ds << 4) + (lane & 15)) * 8;

  int cur = 0, nx = 1;
  for (int kn = 0; kn < KK; ++kn) {
    // (1) B fragments — issued FIRST (short-latency; MFMA's vmcnt stops here)
    v8s bf0[4], bf1[4];
    {
      const ushort* bb0 = bbase + (size_t)(8 * kn) * 2048;
      const ushort* bb1 = bb0 + 4 * 2048;
      #pragma unroll
      for (int nt = 0; nt < 4; ++nt) {
        bf0[nt] = *(const v8s*)(bb0 + nt * 512);
        bf1[nt] = *(const v8s*)(bb1 + nt * 512);
      }
    }
    // (2) EARLY COMMIT: gather(kn+1), in flight since last iteration -> As[nx]
    if (kn + 1 < KK) {
      *(uint4*)(&sm.g.As[nx][r0 * 64 + sc0 * 8]) = R0;
    }
    // (3) issue gather(kn+2) -> R; stays outstanding across the barrier
    R0 = make_uint4(0u,0u,0u,0u);
    if (kn + 2 < KK) {
      int j0 = sm.g.jm[r0][kn + 2];
      if (j0 >= 0) R0 = *(const uint4*)(v + (size_t)j0 * PC + cc0 * 8);
    }
    // (4) A fragments + MFMA on As[cur]: rows rh*32 + mt*16, cols nt*64+ds*16
    #pragma unroll
    for (int s2 = 0; s2 < 2; ++s2) {
      v8s af[2];
      const int cc = s2 * 4 + (lane >> 4);
      #pragma unroll
      for (int mt = 0; mt < 2; ++mt) {
        const int r = rh * 32 + mt * 16 + (lane & 15);
        const int sc = cc ^ (r & 7);
        af[mt] = *(const v8s*)(&sm.g.As[cur][r * 64 + sc * 8]);
      }
      #pragma unroll
      for (int mt = 0; mt < 2; ++mt)
        #pragma unroll
        for (int nt = 0; nt < 4; ++nt)
          acc[mt][nt] = __builtin_amdgcn_mfma_f32_16x16x32_bf16(
              af[mt], (s2 ? bf1[nt] : bf0[nt]), acc[mt][nt], 0, 0, 0);
    }
    __syncthreads();
    cur = nx; nx = (nx == 2) ? 0 : nx + 1;
  }

  // ---- epilogue (no cross-wave traffic): per-lane m-sum + MFMA residual
  for (int i2 = tid; i2 < 2048; i2 += 512) {
    int r = i2 >> 5, c = i2 & 31;
    int n = base + r;
    sm.e.xfb[r][c] = (n < N) ? f2b(xf[(size_t)n * INC + c]) : (ushort)0;
  }
  __syncthreads();

  const int ln = lane & 15, grp = lane >> 4;
  const int d = (ds << 4) + ln;
  // residual = xf @ Wd via 2 MFMAs (K=32)
  v8s wdf = *(const v8s*)(Wdp + (size_t)d * 32 + grp * 8);
  f32x4 res[2];
  #pragma unroll
  for (int mt = 0; mt < 2; ++mt) {
    v8s af = *(const v8s*)(&sm.e.xfb[rh * 32 + mt * 16 + ln][grp * 8]);
    f32x4 z = {0.f, 0.f, 0.f, 0.f};
    res[mt] = __builtin_amdgcn_mfma_f32_16x16x32_bf16(af, wdf, z, 0, 0, 0);
  }
  float bcv[4];
  #pragma unroll
  for (int nt = 0; nt < 4; ++nt) bcv[nt] = bcode[nt * PC + d];
  const float bdv = bd[d];
  #pragma unroll
  for (int mt = 0; mt < 2; ++mt) {
    #pragma unroll
    for (int i = 0; i < 4; ++i) {
      int row = rh * 32 + mt * 16 + grp * 4 + i;
      int n = base + row;
      if (n < N) {
        float4 a4 = *(const float4*)(attn + (size_t)n * 4);
        float val = res[mt][i] + bdv;
        val += a4.x * fmaxf(acc[mt][0][i] + bcv[0], 0.f);
        val += a4.y * fmaxf(acc[mt][1][i] + bcv[1], 0.f);
        val += a4.z * fmaxf(acc[mt][2][i] + bcv[2], 0.f);
        val += a4.w * fmaxf(acc[mt][3][i] + bcv[3], 0.f);
        out[(size_t)n * PC + d] = fmaxf(val, 0.f);
      }
    }
  }
}

extern "C" void kernel_launch(void* const* d_in, const int* in_sizes, int n_in,
                              void* d_out, int out_size, void* d_ws, size_t ws_size,
                              hipStream_t stream)
{
  const float* xf     = (const float*)d_in[0];
  const int* nbr_idx  = (const int*)d_in[1];
  const int* nbr_mask = (const int*)d_in[2];
  const int* coords   = (const int*)d_in[3];
  const float* Wt     = (const float*)d_in[4];
  const float* bt     = (const float*)d_in[5];
  const float* Wd     = (const float*)d_in[6];
  const float* bd     = (const float*)d_in[7];
  const float* Wpos   = (const float*)d_in[8];
  const float* bpos   = (const float*)d_in[9];
  const float* Wq     = (const float*)d_in[10];
  const float* bq     = (const float*)d_in[11];
  const float* proj   = (const float*)d_in[12];
  const float* Wv     = (const float*)d_in[13];
  const float* bv     = (const float*)d_in[14];
  const float* Wcode  = (const float*)d_in[15];
  const float* bcode  = (const float*)d_in[16];
  float* out = (float*)d_out;

  int N = in_sizes[0] / INC;

  char* ws = (char*)d_ws;
  size_t off = 0;
  auto alloc = [&](size_t bytes) {
    off = (off + 255) & ~(size_t)255;
    void* p = ws + off;
    off += bytes;
    return p;
  };
  ushort* x_ws = (ushort*)alloc((size_t)N * PC * 2);
  ushort* v_ws = (ushort*)alloc((size_t)N * PC * 2);
  float*  a_ws = (float*)alloc((size_t)N * 4 * 4);
  ushort* B_ws = (ushort*)alloc((size_t)54 * 4 * 256 * 8 * 2);
  ushort* D_ws = (ushort*)alloc((size_t)2048 * 2);
  (void)ws_size;

  hipLaunchKernelGGL(k_prep, dim3((N + 15) / 16), dim3(256), 0, stream,
                     xf, Wt, bt, Wv, bv, x_ws, v_ws, N);
  hipLaunchKernelGGL(k_attn, dim3((N + 15) / 16), dim3(256), 0, stream,
                     x_ws, nbr_idx, nbr_mask, coords, Wpos, bpos, Wq, bq, proj, a_ws, N);
  hipLaunchKernelGGL(k_prepB, dim3((54 * 4 * 256 * 8) / 256), dim3(256), 0, stream,
                     Wcode, B_ws);
  hipLaunchKernelGGL(k_prepD, dim3(8), dim3(256), 0, stream, Wd, D_ws);
  hipLaunchKernelGGL(k_code, dim3((N + 63) / 64), dim3(512), 0, stream,
                     v_ws, nbr_idx, nbr_mask, B_ws, a_ws, xf, D_ws, bd, bcode, out, N);
}

// Round 11
// 262.748 us; speedup vs baseline: 1.1874x; 1.1874x over previous
//
#include <hip/hip_runtime.h>

#define KK 27
#define INC 32
#define PC 64

typedef __attribute__((ext_vector_type(8))) short v8s;
typedef __attribute__((ext_vector_type(4))) float f32x4;

static __device__ __forceinline__ float b2f(ushort u) {
  union { float f; unsigned int i; } x; x.i = ((unsigned int)u) << 16; return x.f;
}
static __device__ __forceinline__ ushort f2b(float f) {
  union { float f; unsigned int i; } x; x.f = f;
  unsigned int u = x.i;
  unsigned int r = (u + 0x7FFFu + ((u >> 16) & 1u)) >> 16;
  return (ushort)r;
}

// ---------------- Kernel 1: x = relu(xf@Wt+bt) [bf16], v = relu(x@Wv+bv) [bf16]
__global__ __launch_bounds__(256) void k_prep(
    const float* __restrict__ xf, const float* __restrict__ Wt, const float* __restrict__ bt,
    const float* __restrict__ Wv, const float* __restrict__ bv,
    ushort* __restrict__ x, ushort* __restrict__ v, int N)
{
  int tid = threadIdx.x, lane = tid & 63, w = tid >> 6;
  int vbase = blockIdx.x * 16;
  __shared__ float xin[16][32];
  __shared__ float xs[16][64];
  if (tid < 128) {
    int r = tid >> 3, c4 = tid & 7;
    int n = vbase + r;
    float4 d = make_float4(0.f, 0.f, 0.f, 0.f);
    if (n < N) d = *(const float4*)(xf + (size_t)n * INC + c4 * 4);
    *(float4*)(&xin[r][c4 * 4]) = d;
  }
  __syncthreads();
  float a0 = bt[lane], a1 = a0, a2 = a0, a3 = a0;
  #pragma unroll
  for (int i = 0; i < INC; ++i) {
    float wt = Wt[i * PC + lane];
    a0 += xin[w * 4 + 0][i] * wt; a1 += xin[w * 4 + 1][i] * wt;
    a2 += xin[w * 4 + 2][i] * wt; a3 += xin[w * 4 + 3][i] * wt;
  }
  a0 = fmaxf(a0, 0.f); a1 = fmaxf(a1, 0.f); a2 = fmaxf(a2, 0.f); a3 = fmaxf(a3, 0.f);
  xs[w * 4 + 0][lane] = a0; xs[w * 4 + 1][lane] = a1;
  xs[w * 4 + 2][lane] = a2; xs[w * 4 + 3][lane] = a3;
  {
    int n0 = vbase + w * 4;
    if (n0 + 0 < N) x[(size_t)(n0 + 0) * PC + lane] = f2b(a0);
    if (n0 + 1 < N) x[(size_t)(n0 + 1) * PC + lane] = f2b(a1);
    if (n0 + 2 < N) x[(size_t)(n0 + 2) * PC + lane] = f2b(a2);
    if (n0 + 3 < N) x[(size_t)(n0 + 3) * PC + lane] = f2b(a3);
  }
  float v0 = bv[lane], v1 = v0, v2 = v0, v3 = v0;
  #pragma unroll
  for (int i = 0; i < PC; ++i) {
    float wv = Wv[i * PC + lane];
    v0 += xs[w * 4 + 0][i] * wv; v1 += xs[w * 4 + 1][i] * wv;
    v2 += xs[w * 4 + 2][i] * wv; v3 += xs[w * 4 + 3][i] * wv;
  }
  {
    int n0 = vbase + w * 4;
    if (n0 + 0 < N) v[(size_t)(n0 + 0) * PC + lane] = f2b(fmaxf(v0, 0.f));
    if (n0 + 1 < N) v[(size_t)(n0 + 1) * PC + lane] = f2b(fmaxf(v1, 0.f));
    if (n0 + 2 < N) v[(size_t)(n0 + 2) * PC + lane] = f2b(fmaxf(v2, 0.f));
    if (n0 + 3 < N) v[(size_t)(n0 + 3) * PC + lane] = f2b(fmaxf(v3, 0.f));
  }
}

// ---------------- Kernel 2: repack W_code -> Bp, and Wd -> Wdp (fused)
__global__ __launch_bounds__(256) void k_prepBD(
    const float* __restrict__ Wcode, const float* __restrict__ Wd,
    ushort* __restrict__ Bp, ushort* __restrict__ Wdp)
{
  int bid = blockIdx.x;
  if (bid < 1728) {
    int i = bid * 256 + threadIdx.x;   // 54*4*256*8 = 442368
    int j = i & 7;
    int col = (i >> 3) & 255;
    int kg = (i >> 11) & 3;
    int s = i >> 13;
    int k = s * 32 + kg * 8 + j;
    int m = col >> 6, d = col & 63;
    int knbr = k >> 6, c = k & 63;
    Bp[i] = f2b(Wcode[(((m * KK + knbr) * 64) + c) * 64 + d]);
  } else {
    int i = (bid - 1728) * 256 + threadIdx.x;   // 2048
    int col = i >> 5, k = i & 31;
    Wdp[i] = f2b(Wd[k * PC + col]);
  }
}

// ---------------- Kernel 3: gathered GEMM [64x1728]x[1728x256] with FUSED
// q/attn: x-row chunks + neighbor coords prefetched alongside v-gathers;
// per-thread 8-ch q partial accumulated in-loop (co-issues with MFMA);
// shfl-reduce + in-block softmax -> attnL in LDS. R9 GEMM core (4x4 acc,
// 3-buffer ring, early commit, B-before-gather). Per-lane m-sum epilogue.
__global__ __launch_bounds__(256) void k_code(
    const ushort* __restrict__ v, const ushort* __restrict__ x,
    const int* __restrict__ nbr_idx, const int* __restrict__ nbr_mask,
    const ushort* __restrict__ Bp, const int* __restrict__ coords,
    const float* __restrict__ Wpos, const float* __restrict__ bpos,
    const float* __restrict__ Wq, const float* __restrict__ bq,
    const float* __restrict__ proj,
    const float* __restrict__ xf, const ushort* __restrict__ Wdp,
    const float* __restrict__ bd, const float* __restrict__ bcode,
    float* __restrict__ out, int N)
{
  const int tid = threadIdx.x;
  const int lane = tid & 63, w = tid >> 6;
  const int base = blockIdx.x * 64;

  __shared__ __align__(16) union SM {
    struct { ushort As[3][4096]; int jm[64][KK]; } g;   // GEMM phase (31.5 KB)
    struct { ushort xfb[64][40]; } e;                   // epilogue (5.1 KB)
  } sm;
  __shared__ __align__(16) float attnL[64][4];          // survives both phases (1 KB)

  for (int i = tid; i < 64 * KK; i += 256) {
    int r = i / KK, k = i % KK;
    int n = base + r;
    int val = -1;
    if (n < N && nbr_mask[(size_t)n * KK + k]) val = nbr_idx[(size_t)n * KK + k];
    sm.g.jm[r][k] = val;
  }

  const int r0 = tid >> 3, cc0 = tid & 7;
  const int r1 = r0 + 32;
  const int sc0 = cc0 ^ (r0 & 7), sc1 = cc0 ^ (r1 & 7);
  const int ch0 = cc0 * 8;

  __syncthreads();  // jm ready

  // own coords (guarded: base+63 can exceed N)
  const int n0g = base + r0, n1g = base + r1;
  int cx0 = 0, cy0 = 0, cz0 = 0, cx1 = 0, cy1 = 0, cz1 = 0;
  if (n0g < N) { cx0 = coords[n0g * 3]; cy0 = coords[n0g * 3 + 1]; cz0 = coords[n0g * 3 + 2]; }
  if (n1g < N) { cx1 = coords[n1g * 3]; cy1 = coords[n1g * 3 + 1]; cz1 = coords[n1g * 3 + 2]; }
  // pos-MLP weights for my 8 channels (loop-invariant)
  float wpr0[8], wpr1[8], wpr2[8], bpr[8];
  #pragma unroll
  for (int c = 0; c < 8; ++c) {
    wpr0[c] = Wpos[ch0 + c];
    wpr1[c] = Wpos[64 + ch0 + c];
    wpr2[c] = Wpos[128 + ch0 + c];
    bpr[c]  = bpos[ch0 + c];
  }
  const float bq0 = bq[0];
  float pj[4];
  #pragma unroll
  for (int m = 0; m < 4; ++m) pj[m] = proj[m] * 0.1f;

  // prologue: v(0) -> As[0]; v(1) -> R; x(0)+coords(0) -> regs
  uint4 R0 = make_uint4(0u,0u,0u,0u), R1 = R0;
  uint4 xC0, xC1;
  int nx0, ny0, nz0, nx1, ny1, nz1;
  float mc0, mc1;
  {
    int ja = sm.g.jm[r0][0], jb = sm.g.jm[r1][0];
    uint4 p0 = make_uint4(0u, 0u, 0u, 0u), p1 = p0;
    if (ja >= 0) p0 = *(const uint4*)(v + (size_t)ja * PC + ch0);
    if (jb >= 0) p1 = *(const uint4*)(v + (size_t)jb * PC + ch0);
    int jc = sm.g.jm[r0][1], jd = sm.g.jm[r1][1];
    if (jc >= 0) R0 = *(const uint4*)(v + (size_t)jc * PC + ch0);
    if (jd >= 0) R1 = *(const uint4*)(v + (size_t)jd * PC + ch0);
    int jja = max(ja, 0), jjb = max(jb, 0);
    xC0 = *(const uint4*)(x + (size_t)jja * PC + ch0);
    xC1 = *(const uint4*)(x + (size_t)jjb * PC + ch0);
    nx0 = coords[jja * 3]; ny0 = coords[jja * 3 + 1]; nz0 = coords[jja * 3 + 2];
    nx1 = coords[jjb * 3]; ny1 = coords[jjb * 3 + 1]; nz1 = coords[jjb * 3 + 2];
    mc0 = (ja >= 0) ? 1.f : 0.f; mc1 = (jb >= 0) ? 1.f : 0.f;
    *(uint4*)(&sm.g.As[0][r0 * 64 + sc0 * 8]) = p0;
    *(uint4*)(&sm.g.As[0][r1 * 64 + sc1 * 8]) = p1;
  }
  __syncthreads();

  f32x4 acc[4][4] = {};
  float qp0 = 0.f, qp1 = 0.f;
  // col = nt*64 + w*16 + (lane&15)  -> nt stride = 512 ushorts
  const ushort* bbase = Bp + (size_t)(lane >> 4) * 2048 + (size_t)((w << 4) + (lane & 15)) * 8;

  int cur = 0, nxb = 1;
  for (int kn = 0; kn < KK; ++kn) {
    // (1) B fragments — FIRST (MFMA's vmcnt stops here)
    v8s bf0[4], bf1[4];
    {
      const ushort* bb0 = bbase + (size_t)(8 * kn) * 2048;
      const ushort* bb1 = bb0 + 4 * 2048;
      #pragma unroll
      for (int nt = 0; nt < 4; ++nt) {
        bf0[nt] = *(const v8s*)(bb0 + nt * 512);
        bf1[nt] = *(const v8s*)(bb1 + nt * 512);
      }
    }
    // (1.5) Wq for this kn (L1-hot; q's wait retires <= here, keeps v(kn+2) outstanding)
    float4 wqA = *(const float4*)(Wq + kn * PC + ch0);
    float4 wqB = *(const float4*)(Wq + kn * PC + ch0 + 4);
    // (2) EARLY COMMIT: v(kn+1), in flight since last iteration -> As[nxb]
    if (kn + 1 < KK) {
      *(uint4*)(&sm.g.As[nxb][r0 * 64 + sc0 * 8]) = R0;
      *(uint4*)(&sm.g.As[nxb][r1 * 64 + sc1 * 8]) = R1;
    }
    // (3) prefetch x(kn+1) + neighbor coords(kn+1)
    uint4 xN0 = xC0, xN1 = xC1;
    int mx0 = nx0, my0 = ny0, mz0 = nz0, mx1 = nx1, my1 = ny1, mz1 = nz1;
    float mn0 = 0.f, mn1 = 0.f;
    if (kn + 1 < KK) {
      int ja = sm.g.jm[r0][kn + 1], jb = sm.g.jm[r1][kn + 1];
      int jja = max(ja, 0), jjb = max(jb, 0);
      xN0 = *(const uint4*)(x + (size_t)jja * PC + ch0);
      xN1 = *(const uint4*)(x + (size_t)jjb * PC + ch0);
      mx0 = coords[jja * 3]; my0 = coords[jja * 3 + 1]; mz0 = coords[jja * 3 + 2];
      mx1 = coords[jjb * 3]; my1 = coords[jjb * 3 + 1]; mz1 = coords[jjb * 3 + 2];
      mn0 = (ja >= 0) ? 1.f : 0.f; mn1 = (jb >= 0) ? 1.f : 0.f;
    }
    // (4) issue v(kn+2) -> R; stays outstanding across the barrier
    R0 = make_uint4(0u,0u,0u,0u); R1 = R0;
    if (kn + 2 < KK) {
      int j0 = sm.g.jm[r0][kn + 2], j1 = sm.g.jm[r1][kn + 2];
      if (j0 >= 0) R0 = *(const uint4*)(v + (size_t)j0 * PC + ch0);
      if (j1 >= 0) R1 = *(const uint4*)(v + (size_t)j1 * PC + ch0);
    }
    // (5) q-compute for kn (VALU; co-issues with MFMA pipe)
    {
      float wqv[8] = {wqA.x, wqA.y, wqA.z, wqA.w, wqB.x, wqB.y, wqB.z, wqB.w};
      float rx0 = (float)(nx0 - cx0), ry0 = (float)(ny0 - cy0), rz0 = (float)(nz0 - cz0);
      float rx1 = (float)(nx1 - cx1), ry1 = (float)(ny1 - cy1), rz1 = (float)(nz1 - cz1);
      const ushort* xa = (const ushort*)&xC0;
      const ushort* xb = (const ushort*)&xC1;
      float t0 = 0.f, t1 = 0.f;
      #pragma unroll
      for (int c = 0; c < 8; ++c) {
        float p0 = fmaxf(rx0 * wpr0[c] + ry0 * wpr1[c] + rz0 * wpr2[c] + bpr[c], 0.f);
        float p1 = fmaxf(rx1 * wpr0[c] + ry1 * wpr1[c] + rz1 * wpr2[c] + bpr[c], 0.f);
        t0 += (b2f(xa[c]) + p0) * wqv[c];
        t1 += (b2f(xb[c]) + p1) * wqv[c];
      }
      qp0 += mc0 * t0;
      qp1 += mc1 * t1;
    }
    // (6) A fragments + MFMA on As[cur]
    #pragma unroll
    for (int s2 = 0; s2 < 2; ++s2) {
      v8s af[4];
      const int cc = s2 * 4 + (lane >> 4);
      #pragma unroll
      for (int mt = 0; mt < 4; ++mt) {
        const int r = mt * 16 + (lane & 15);
        const int sc = cc ^ (r & 7);
        af[mt] = *(const v8s*)(&sm.g.As[cur][r * 64 + sc * 8]);
      }
      #pragma unroll
      for (int mt = 0; mt < 4; ++mt)
        #pragma unroll
        for (int nt = 0; nt < 4; ++nt)
          acc[mt][nt] = __builtin_amdgcn_mfma_f32_16x16x32_bf16(
              af[mt], (s2 ? bf1[nt] : bf0[nt]), acc[mt][nt], 0, 0, 0);
    }
    __syncthreads();
    cur = nxb; nxb = (nxb == 2) ? 0 : nxb + 1;
    xC0 = xN0; xC1 = xN1;
    nx0 = mx0; ny0 = my0; nz0 = mz0; nx1 = mx1; ny1 = my1; nz1 = mz1;
    mc0 = mn0; mc1 = mn1;
  }

  // ---- q reduce (8 lanes per row) + softmax -> attnL
  qp0 += __shfl_xor(qp0, 1); qp0 += __shfl_xor(qp0, 2); qp0 += __shfl_xor(qp0, 4);
  qp1 += __shfl_xor(qp1, 1); qp1 += __shfl_xor(qp1, 2); qp1 += __shfl_xor(qp1, 4);
  if (cc0 == 0) {
    float qs[2] = {qp0, qp1};
    int rr[2] = {r0, r1};
    #pragma unroll
    for (int h = 0; h < 2; ++h) {
      float q = fmaxf(qs[h] + bq0, 0.f);
      float lg[4], mx = -1e30f;
      #pragma unroll
      for (int m = 0; m < 4; ++m) { lg[m] = q * pj[m]; mx = fmaxf(mx, lg[m]); }
      float s = 0.f;
      #pragma unroll
      for (int m = 0; m < 4; ++m) { lg[m] = __expf(lg[m] - mx); s += lg[m]; }
      float inv = 1.f / s;
      #pragma unroll
      for (int m = 0; m < 4; ++m) attnL[rr[h]][m] = lg[m] * inv;
    }
  }

  // ---- epilogue: per-lane m-sum + MFMA residual
  for (int i2 = tid; i2 < 2048; i2 += 256) {
    int r = i2 >> 5, c = i2 & 31;
    int n = base + r;
    sm.e.xfb[r][c] = (n < N) ? f2b(xf[(size_t)n * INC + c]) : (ushort)0;
  }
  __syncthreads();

  const int ln = lane & 15, grp = lane >> 4;
  const int d = (w << 4) + ln;
  v8s wdf = *(const v8s*)(Wdp + (size_t)d * 32 + grp * 8);
  f32x4 res[4];
  #pragma unroll
  for (int mt = 0; mt < 4; ++mt) {
    v8s af = *(const v8s*)(&sm.e.xfb[mt * 16 + ln][grp * 8]);
    f32x4 z = {0.f, 0.f, 0.f, 0.f};
    res[mt] = __builtin_amdgcn_mfma_f32_16x16x32_bf16(af, wdf, z, 0, 0, 0);
  }
  float bcv[4];
  #pragma unroll
  for (int nt = 0; nt < 4; ++nt) bcv[nt] = bcode[nt * PC + d];
  const float bdv = bd[d];
  #pragma unroll
  for (int mt = 0; mt < 4; ++mt) {
    #pragma unroll
    for (int i = 0; i < 4; ++i) {
      int row = mt * 16 + grp * 4 + i;
      int n = base + row;
      if (n < N) {
        float4 a4 = *(const float4*)(&attnL[row][0]);
        float val = res[mt][i] + bdv;
        val += a4.x * fmaxf(acc[mt][0][i] + bcv[0], 0.f);
        val += a4.y * fmaxf(acc[mt][1][i] + bcv[1], 0.f);
        val += a4.z * fmaxf(acc[mt][2][i] + bcv[2], 0.f);
        val += a4.w * fmaxf(acc[mt][3][i] + bcv[3], 0.f);
        out[(size_t)n * PC + d] = fmaxf(val, 0.f);
      }
    }
  }
}

extern "C" void kernel_launch(void* const* d_in, const int* in_sizes, int n_in,
                              void* d_out, int out_size, void* d_ws, size_t ws_size,
                              hipStream_t stream)
{
  const float* xf     = (const float*)d_in[0];
  const int* nbr_idx  = (const int*)d_in[1];
  const int* nbr_mask = (const int*)d_in[2];
  const int* coords   = (const int*)d_in[3];
  const float* Wt     = (const float*)d_in[4];
  const float* bt     = (const float*)d_in[5];
  const float* Wd     = (const float*)d_in[6];
  const float* bd     = (const float*)d_in[7];
  const float* Wpos   = (const float*)d_in[8];
  const float* bpos   = (const float*)d_in[9];
  const float* Wq     = (const float*)d_in[10];
  const float* bq     = (const float*)d_in[11];
  const float* proj   = (const float*)d_in[12];
  const float* Wv     = (const float*)d_in[13];
  const float* bv     = (const float*)d_in[14];
  const float* Wcode  = (const float*)d_in[15];
  const float* bcode  = (const float*)d_in[16];
  float* out = (float*)d_out;

  int N = in_sizes[0] / INC;

  char* ws = (char*)d_ws;
  size_t off = 0;
  auto alloc = [&](size_t bytes) {
    off = (off + 255) & ~(size_t)255;
    void* p = ws + off;
    off += bytes;
    return p;
  };
  ushort* x_ws = (ushort*)alloc((size_t)N * PC * 2);
  ushort* v_ws = (ushort*)alloc((size_t)N * PC * 2);
  ushort* B_ws = (ushort*)alloc((size_t)54 * 4 * 256 * 8 * 2);
  ushort* D_ws = (ushort*)alloc((size_t)2048 * 2);
  (void)ws_size;

  hipLaunchKernelGGL(k_prepBD, dim3(1736), dim3(256), 0, stream,
                     Wcode, Wd, B_ws, D_ws);
  hipLaunchKernelGGL(k_prep, dim3((N + 15) / 16), dim3(256), 0, stream,
                     xf, Wt, bt, Wv, bv, x_ws, v_ws, N);
  hipLaunchKernelGGL(k_code, dim3((N + 63) / 64), dim3(256), 0, stream,
                     v_ws, x_ws, nbr_idx, nbr_mask, B_ws, coords,
                     Wpos, bpos, Wq, bq, proj, xf, D_ws, bd, bcode, out, N);
}